// Round 11
// baseline (1400.068 us; speedup 1.0000x reference)
//
#include <hip/hip_runtime.h>
#include <hip/hip_bf16.h>
#include <math.h>

// out = LN2( gelu_erf( LN1(x) @ W^T + bW ) )
// x: [4,4096,2048] f32 -> M=16384 rows. W: [2048,2048] f32, C[m,e]=sum_d h[m,d]*W[e,d].
// R11: 256x256 tile, BK=32, ring-2 dbuf, 64KB LDS -> TWO blocks/CU (vs 1 in R4-R8).
// Same LDS layout/swizzle/staging as R4 (proven fastest). vmcnt(0)+BAR per slice; the
// drain is covered by the co-resident block (occupancy mechanism under test).
// ln1+Wcvt fused into one launch; GEMM epilogue writes bf16 h2; LN2 reads bf16.

#define D 2048
#define MROWS 16384
#define BMT 256
#define BNT 256
#define NS 64

typedef __bf16 bf16x8 __attribute__((ext_vector_type(8)));
typedef float f32x4 __attribute__((ext_vector_type(4)));

#define GLP(p) ((const __attribute__((address_space(1))) void*)(p))
#define LDSP(p) ((__attribute__((address_space(3))) void*)(p))
#define S_VMCNT(n) asm volatile("s_waitcnt vmcnt(" #n ")" ::: "memory")
#define MEMFENCE() asm volatile("" ::: "memory")
#define BAR() __builtin_amdgcn_s_barrier()
#define SCHED_FENCE() __builtin_amdgcn_sched_barrier(0)

__device__ __forceinline__ float gelu_f(float v) {
  return 0.5f * v * (1.0f + erff(v * 0.70710678118654752f));
}

// ---------------- LN1 (rows) + W cvt (tail blocks), fused ----------------
__global__ __launch_bounds__(256) void ln1f_kernel(
    const float* __restrict__ x, const float* __restrict__ g,
    const float* __restrict__ b, __hip_bfloat16* __restrict__ outA,
    const float* __restrict__ W, __hip_bfloat16* __restrict__ Wb) {
  const int tid = threadIdx.x;
  const int bid = blockIdx.x;
  if (bid >= MROWS) {
    const int i = (bid - MROWS) * 256 + tid;          // 0 .. D*D/8-1
    const float4* p = (const float4*)W + 2 * (size_t)i;
    float4 a = p[0], c = p[1];
    alignas(16) __hip_bfloat16 h[8] = {
        __float2bfloat16(a.x), __float2bfloat16(a.y),
        __float2bfloat16(a.z), __float2bfloat16(a.w),
        __float2bfloat16(c.x), __float2bfloat16(c.y),
        __float2bfloat16(c.z), __float2bfloat16(c.w)};
    *(uint4*)(Wb + (size_t)i * 8) = *(const uint4*)h;
    return;
  }
  const size_t row = bid;
  const float4* xr = (const float4*)(x + row * D);
  float4 v0 = xr[2 * tid];
  float4 v1 = xr[2 * tid + 1];
  float s  = v0.x + v0.y + v0.z + v0.w + v1.x + v1.y + v1.z + v1.w;
  float ss = v0.x*v0.x + v0.y*v0.y + v0.z*v0.z + v0.w*v0.w
           + v1.x*v1.x + v1.y*v1.y + v1.z*v1.z + v1.w*v1.w;
#pragma unroll
  for (int off = 32; off > 0; off >>= 1) {
    s  += __shfl_down(s, off, 64);
    ss += __shfl_down(ss, off, 64);
  }
  __shared__ float red[8];
  const int w = tid >> 6;
  if ((tid & 63) == 0) { red[w] = s; red[w + 4] = ss; }
  __syncthreads();
  s  = red[0] + red[1] + red[2] + red[3];
  ss = red[4] + red[5] + red[6] + red[7];
  const float mu  = s * (1.0f / D);
  const float var = ss * (1.0f / D) - mu * mu;
  const float inv = rsqrtf(var + 1e-5f);
  const float4* gv = (const float4*)g;
  const float4* bv = (const float4*)b;
  float4 g0 = gv[2 * tid], g1 = gv[2 * tid + 1];
  float4 b0 = bv[2 * tid], b1 = bv[2 * tid + 1];
  alignas(16) __hip_bfloat16 h[8];
  h[0] = __float2bfloat16((v0.x - mu) * inv * g0.x + b0.x);
  h[1] = __float2bfloat16((v0.y - mu) * inv * g0.y + b0.y);
  h[2] = __float2bfloat16((v0.z - mu) * inv * g0.z + b0.z);
  h[3] = __float2bfloat16((v0.w - mu) * inv * g0.w + b0.w);
  h[4] = __float2bfloat16((v1.x - mu) * inv * g1.x + b1.x);
  h[5] = __float2bfloat16((v1.y - mu) * inv * g1.y + b1.y);
  h[6] = __float2bfloat16((v1.z - mu) * inv * g1.z + b1.z);
  h[7] = __float2bfloat16((v1.w - mu) * inv * g1.w + b1.w);
  *(uint4*)(outA + row * D + (size_t)tid * 8) = *(const uint4*)h;
}

// ---------------- GEMM: 256x256, BK=32, ring-2, 64KB LDS, 2 blocks/CU ----------------
// Slice region (s&1)*16KB per operand = 256 rows x 32 cols bf16 as 128 lines x 128B;
// (row, chunk lk) at line=row>>1, slot=(2*lk+(row&1))^((row>>1)&7). DMA dest linear;
// inverse swizzle on the global SOURCE (R4-proven layout).
template <bool BFO>
__global__ __launch_bounds__(512, 4) void gemm_kernel(
    const __hip_bfloat16* __restrict__ A,
    const __hip_bfloat16* __restrict__ Bw,
    const float* __restrict__ bias,
    void* __restrict__ Cout) {
  __shared__ __hip_bfloat16 sA[2 * 256 * 32];  // 32KB
  __shared__ __hip_bfloat16 sB[2 * 256 * 32];  // 32KB
  const int tid = threadIdx.x;
  const int l = tid & 63;
  const int wid = tid >> 6;
  const int fr = l & 15;
  const int lk = l >> 4;
  const size_t m0 = (size_t)blockIdx.x * BMT;
  const int n0 = blockIdx.y * BNT;
  const int whm = wid >> 2;
  const int wn = (wid & 3) * 64;

  const int slot = ((2 * lk + (fr & 1)) ^ (fr >> 1)) << 4;
  const int aoff = whm * 8192 + (fr >> 1) * 128 + slot;
  const int boff = wn * 64 + (fr >> 1) * 128 + slot;

  const int line = tid >> 3;
  const int v = (tid & 7) ^ (line & 7);
  const int srow0 = 2 * line + (v & 1);
  const int srow1 = srow0 + 128;
  const int scol = (v >> 1) * 8;
  const int ldd0 = tid * 16;
  const int ldd1 = ldd0 + 8192;
  const __hip_bfloat16* const Ag = A + m0 * D;
  const __hip_bfloat16* const Bg = Bw + (size_t)n0 * D;

  auto stg = [&](const __hip_bfloat16* G, char* lds, int s) {  // 2 x global_load_lds(16B)
    const __hip_bfloat16* s0 = G + (size_t)srow0 * D + s * 32 + scol;
    const __hip_bfloat16* s1 = G + (size_t)srow1 * D + s * 32 + scol;
    char* q = lds + ((s & 1) << 14);
    __builtin_amdgcn_global_load_lds(GLP(s0), LDSP(q + ldd0), 16, 0, 0);
    __builtin_amdgcn_global_load_lds(GLP(s1), LDSP(q + ldd1), 16, 0, 0);
  };

  bf16x8 a[8], b[4];
  f32x4 acc[8][4] = {};

  auto rd = [&](int s) {
    const char* pa = (const char*)sA + ((s & 1) << 14) + aoff;
    const char* pb = (const char*)sB + ((s & 1) << 14) + boff;
#pragma unroll
    for (int mi = 0; mi < 8; ++mi) a[mi] = *(const bf16x8*)(pa + mi * 1024);
#pragma unroll
    for (int ni = 0; ni < 4; ++ni) b[ni] = *(const bf16x8*)(pb + ni * 1024);
  };
  auto mma = [&]() {
    __builtin_amdgcn_s_setprio(1);
#pragma unroll
    for (int mi = 0; mi < 8; ++mi)
#pragma unroll
      for (int ni = 0; ni < 4; ++ni)
        acc[mi][ni] = __builtin_amdgcn_mfma_f32_16x16x32_bf16(a[mi], b[ni], acc[mi][ni], 0, 0, 0);
    __builtin_amdgcn_s_setprio(0);
  };

  // prologue: stage slice 0 into buf0
  stg(Ag, (char*)sA, 0); stg(Bg, (char*)sB, 0);

  // body(s): vmcnt(0) [all staged DMA landed]; BAR; read slice s from buf s&1;
  // stage slice s+1 into buf (s+1)&1 (opposite -> no read/write overlap); 32 MFMA.
  // Reads of buf s&1 are consumed by each wave's mma before it reaches BAR(s+1),
  // and the overwriting stg(s+2) is issued only after BAR(s+1) -> safe.
  for (int s = 0; s < NS; ++s) {
    S_VMCNT(0);
    BAR(); MEMFENCE(); SCHED_FENCE();
    rd(s);
    if (s + 1 < NS) { stg(Ag, (char*)sA, s + 1); stg(Bg, (char*)sB, s + 1); }
    mma();
  }

  // epilogue: bias + gelu (C/D: col=lane&15, row=(lane>>4)*4+reg)
  float bv[4];
#pragma unroll
  for (int ni = 0; ni < 4; ++ni) bv[ni] = bias[n0 + wn + ni * 16 + fr];
#pragma unroll
  for (int mi = 0; mi < 8; ++mi) {
    const size_t rbase = m0 + whm * 128 + mi * 16 + lk * 4;
#pragma unroll
    for (int rr = 0; rr < 4; ++rr) {
      const size_t ro = (rbase + rr) * D + n0 + wn + fr;
#pragma unroll
      for (int ni = 0; ni < 4; ++ni) {
        const float val = gelu_f(acc[mi][ni][rr] + bv[ni]);
        if constexpr (BFO)
          ((__hip_bfloat16*)Cout)[ro + ni * 16] = __float2bfloat16(val);
        else
          ((float*)Cout)[ro + ni * 16] = val;
      }
    }
  }
}

// ---------------- LN2 (f32 in-place fallback) ----------------
__global__ __launch_bounds__(256) void ln2_kernel(
    float* __restrict__ C, const float* __restrict__ g, const float* __restrict__ b) {
  const int tid = threadIdx.x;
  const size_t row = blockIdx.x;
  float4* cr = (float4*)(C + row * D);
  float4 v0 = cr[2 * tid], v1 = cr[2 * tid + 1];
  float s  = v0.x + v0.y + v0.z + v0.w + v1.x + v1.y + v1.z + v1.w;
  float ss = v0.x*v0.x + v0.y*v0.y + v0.z*v0.z + v0.w*v0.w
           + v1.x*v1.x + v1.y*v1.y + v1.z*v1.z + v1.w*v1.w;
#pragma unroll
  for (int off = 32; off > 0; off >>= 1) {
    s  += __shfl_down(s, off, 64);
    ss += __shfl_down(ss, off, 64);
  }
  __shared__ float red[8];
  const int w = tid >> 6;
  if ((tid & 63) == 0) { red[w] = s; red[w + 4] = ss; }
  __syncthreads();
  s  = red[0] + red[1] + red[2] + red[3];
  ss = red[4] + red[5] + red[6] + red[7];
  const float mu  = s * (1.0f / D);
  const float var = ss * (1.0f / D) - mu * mu;
  const float inv = rsqrtf(var + 1e-5f);
  const float4* gv = (const float4*)g;
  const float4* bv = (const float4*)b;
  float4 g0 = gv[2 * tid], g1 = gv[2 * tid + 1];
  float4 b0 = bv[2 * tid], b1 = bv[2 * tid + 1];
  float4 o0, o1;
  o0.x = (v0.x - mu) * inv * g0.x + b0.x;
  o0.y = (v0.y - mu) * inv * g0.y + b0.y;
  o0.z = (v0.z - mu) * inv * g0.z + b0.z;
  o0.w = (v0.w - mu) * inv * g0.w + b0.w;
  o1.x = (v1.x - mu) * inv * g1.x + b1.x;
  o1.y = (v1.y - mu) * inv * g1.y + b1.y;
  o1.z = (v1.z - mu) * inv * g1.z + b1.z;
  o1.w = (v1.w - mu) * inv * g1.w + b1.w;
  cr[2 * tid] = o0;
  cr[2 * tid + 1] = o1;
}

// ---------------- LN2 from bf16 h2 -> f32 out ----------------
__global__ __launch_bounds__(256) void ln2b_kernel(
    const __hip_bfloat16* __restrict__ H, const float* __restrict__ g,
    const float* __restrict__ b, float* __restrict__ out) {
  const int tid = threadIdx.x;
  const size_t row = blockIdx.x;
  const uint4 hv = ((const uint4*)(H + row * D))[tid];   // 8 bf16
  float v[8];
  const unsigned wds[4] = {hv.x, hv.y, hv.z, hv.w};
#pragma unroll
  for (int i = 0; i < 4; ++i) {
    unsigned lo = (wds[i] & 0xffffu) << 16;
    unsigned hi = wds[i] & 0xffff0000u;
    v[2 * i]     = __builtin_bit_cast(float, lo);
    v[2 * i + 1] = __builtin_bit_cast(float, hi);
  }
  float s = 0.f, ss = 0.f;
#pragma unroll
  for (int i = 0; i < 8; ++i) { s += v[i]; ss += v[i] * v[i]; }
#pragma unroll
  for (int off = 32; off > 0; off >>= 1) {
    s  += __shfl_down(s, off, 64);
    ss += __shfl_down(ss, off, 64);
  }
  __shared__ float red[8];
  const int w = tid >> 6;
  if ((tid & 63) == 0) { red[w] = s; red[w + 4] = ss; }
  __syncthreads();
  s  = red[0] + red[1] + red[2] + red[3];
  ss = red[4] + red[5] + red[6] + red[7];
  const float mu  = s * (1.0f / D);
  const float var = ss * (1.0f / D) - mu * mu;
  const float inv = rsqrtf(var + 1e-5f);
  const float4* gv = (const float4*)g;
  const float4* bv = (const float4*)b;
  float4 g0 = gv[2 * tid], g1 = gv[2 * tid + 1];
  float4 b0 = bv[2 * tid], b1 = bv[2 * tid + 1];
  float4 o0, o1;
  o0.x = (v[0] - mu) * inv * g0.x + b0.x;
  o0.y = (v[1] - mu) * inv * g0.y + b0.y;
  o0.z = (v[2] - mu) * inv * g0.z + b0.z;
  o0.w = (v[3] - mu) * inv * g0.w + b0.w;
  o1.x = (v[4] - mu) * inv * g1.x + b1.x;
  o1.y = (v[5] - mu) * inv * g1.y + b1.y;
  o1.z = (v[6] - mu) * inv * g1.z + b1.z;
  o1.w = (v[7] - mu) * inv * g1.w + b1.w;
  float4* orow = (float4*)(out + row * D);
  orow[2 * tid] = o0;
  orow[2 * tid + 1] = o1;
}

extern "C" void kernel_launch(void* const* d_in, const int* in_sizes, int n_in,
                              void* d_out, int out_size, void* d_ws, size_t ws_size,
                              hipStream_t stream) {
  const float* x  = (const float*)d_in[0];
  const float* W  = (const float*)d_in[1];
  const float* bW = (const float*)d_in[2];
  const float* g1 = (const float*)d_in[3];
  const float* b1 = (const float*)d_in[4];
  const float* g2 = (const float*)d_in[5];
  const float* b2 = (const float*)d_in[6];
  float* out = (float*)d_out;

  __hip_bfloat16* Abf = (__hip_bfloat16*)d_ws;                    // 67MB
  __hip_bfloat16* Wbf = Abf + (size_t)MROWS * D;                  // +8.4MB
  __hip_bfloat16* H2  = Wbf + (size_t)D * D;                      // +67MB (optional)
  const size_t need = ((size_t)MROWS * D * 2 + (size_t)D * D) * sizeof(__hip_bfloat16);

  ln1f_kernel<<<MROWS + (D * D / 8) / 256, 256, 0, stream>>>(x, g1, b1, Abf, W, Wbf);
  dim3 grid(MROWS / BMT, D / BNT);
  if (ws_size >= need) {
    gemm_kernel<true><<<grid, 512, 0, stream>>>(Abf, Wbf, bW, (void*)H2);
    ln2b_kernel<<<MROWS, 256, 0, stream>>>(H2, g2, b2, out);
  } else {
    gemm_kernel<false><<<grid, 512, 0, stream>>>(Abf, Wbf, bW, (void*)out);
    ln2_kernel<<<MROWS, 256, 0, stream>>>(out, g2, b2);
  }
}

// Round 12
// 234.164 us; speedup vs baseline: 5.9790x; 5.9790x over previous
//
#include <hip/hip_runtime.h>
#include <hip/hip_bf16.h>
#include <math.h>

// out = LN2( gelu_erf( LN1(x) @ W^T + bW ) )
// x: [4,4096,2048] f32 -> M=16384 rows. W: [2048,2048] f32, C[m,e]=sum_d h[m,d]*W[e,d].
// R12: B is PRE-FRAGMENTED in ws by the cvt kernel (WF[by][s][nf][lane][8]) and loaded
// directly global->VGPR in the GEMM (lane-contiguous 1KB frags, L2/L3-resident). LDS holds
// only A (R10 layout/swizzle, ring-4 x 16KB). Mixed counted vmcnt(6): per slice issue
// {2 A-DMA, 4 B-loads}; ldB(s+2) after mma(s). GEMM epilogue -> bf16 h2; LN2 reads bf16.

#define D 2048
#define MROWS 16384
#define BMT 256
#define BNT 256
#define NS 64

typedef __bf16 bf16x8 __attribute__((ext_vector_type(8)));
typedef float f32x4 __attribute__((ext_vector_type(4)));

#define GLP(p) ((const __attribute__((address_space(1))) void*)(p))
#define LDSP(p) ((__attribute__((address_space(3))) void*)(p))
#define S_VMCNT(n) asm volatile("s_waitcnt vmcnt(" #n ")" ::: "memory")
#define MEMFENCE() asm volatile("" ::: "memory")
#define BAR() __builtin_amdgcn_s_barrier()
#define SCHED_FENCE() __builtin_amdgcn_sched_barrier(0)

__device__ __forceinline__ float gelu_f(float v) {
  return 0.5f * v * (1.0f + erff(v * 0.70710678118654752f));
}

// ---------------- LN1: f32 row -> bf16 row ----------------
__global__ __launch_bounds__(256) void ln1_kernel(
    const float* __restrict__ x, const float* __restrict__ g,
    const float* __restrict__ b, __hip_bfloat16* __restrict__ out) {
  const int tid = threadIdx.x;
  const size_t row = blockIdx.x;
  const float4* xr = (const float4*)(x + row * D);
  float4 v0 = xr[2 * tid];
  float4 v1 = xr[2 * tid + 1];
  float s  = v0.x + v0.y + v0.z + v0.w + v1.x + v1.y + v1.z + v1.w;
  float ss = v0.x*v0.x + v0.y*v0.y + v0.z*v0.z + v0.w*v0.w
           + v1.x*v1.x + v1.y*v1.y + v1.z*v1.z + v1.w*v1.w;
#pragma unroll
  for (int off = 32; off > 0; off >>= 1) {
    s  += __shfl_down(s, off, 64);
    ss += __shfl_down(ss, off, 64);
  }
  __shared__ float red[8];
  const int w = tid >> 6;
  if ((tid & 63) == 0) { red[w] = s; red[w + 4] = ss; }
  __syncthreads();
  s  = red[0] + red[1] + red[2] + red[3];
  ss = red[4] + red[5] + red[6] + red[7];
  const float mu  = s * (1.0f / D);
  const float var = ss * (1.0f / D) - mu * mu;
  const float inv = rsqrtf(var + 1e-5f);
  const float4* gv = (const float4*)g;
  const float4* bv = (const float4*)b;
  float4 g0 = gv[2 * tid], g1 = gv[2 * tid + 1];
  float4 b0 = bv[2 * tid], b1 = bv[2 * tid + 1];
  alignas(16) __hip_bfloat16 h[8];
  h[0] = __float2bfloat16((v0.x - mu) * inv * g0.x + b0.x);
  h[1] = __float2bfloat16((v0.y - mu) * inv * g0.y + b0.y);
  h[2] = __float2bfloat16((v0.z - mu) * inv * g0.z + b0.z);
  h[3] = __float2bfloat16((v0.w - mu) * inv * g0.w + b0.w);
  h[4] = __float2bfloat16((v1.x - mu) * inv * g1.x + b1.x);
  h[5] = __float2bfloat16((v1.y - mu) * inv * g1.y + b1.y);
  h[6] = __float2bfloat16((v1.z - mu) * inv * g1.z + b1.z);
  h[7] = __float2bfloat16((v1.w - mu) * inv * g1.w + b1.w);
  *(uint4*)(out + row * D + (size_t)tid * 8) = *(const uint4*)h;
}

// ---------------- W: f32 -> bf16, PRE-FRAGMENTED ----------------
// WF[by(8)][s(64)][nf(16)][lane(64)][8]: element (e,k) at by=e>>8, nf=(e>>4)&15, fr=e&15,
// s=k>>5, lk=(k>>3)&3 -> lane=lk*16+fr, j=k&7.
__global__ __launch_bounds__(256) void cvtf_kernel(
    const float* __restrict__ W, __hip_bfloat16* __restrict__ WF) {
  const int i = blockIdx.x * 256 + threadIdx.x;   // over D*D/8
  const int e = i >> 8;
  const int kc = i & 255;                          // 8-elem k-chunk
  const float4* p = (const float4*)(W + (size_t)e * D + kc * 8);
  float4 a = p[0], c = p[1];
  alignas(16) __hip_bfloat16 h[8] = {
      __float2bfloat16(a.x), __float2bfloat16(a.y),
      __float2bfloat16(a.z), __float2bfloat16(a.w),
      __float2bfloat16(c.x), __float2bfloat16(c.y),
      __float2bfloat16(c.z), __float2bfloat16(c.w)};
  const int by = e >> 8, nf = (e >> 4) & 15, fr = e & 15;
  const int s = kc >> 2, lk = kc & 3;
  const size_t off = ((((size_t)by * 64 + s) * 16 + nf) * 64 + lk * 16 + fr) * 8;
  *(uint4*)(WF + off) = *(const uint4*)h;
}

// ---------------- GEMM: 256x256, 8 waves (2M x 4N), A-LDS ring-4, B-direct ----------------
template <bool BFO>
__global__ __launch_bounds__(512, 2) void gemm_kernel(
    const __hip_bfloat16* __restrict__ A,
    const __hip_bfloat16* __restrict__ WF,
    const float* __restrict__ bias,
    void* __restrict__ Cout) {
  __shared__ __hip_bfloat16 sA[4 * 8192];   // 64KB: ring of 4 A slice regions (16KB each)
  const int tid = threadIdx.x;
  const int l = tid & 63;
  const int wid = tid >> 6;
  const int fr = l & 15;
  const int lk = l >> 4;
  const size_t m0 = (size_t)blockIdx.x * BMT;
  const int n0 = blockIdx.y * BNT;
  const int whm = wid >> 2;
  const int wn = (wid & 3) * 64;

  // A LDS: region = 256 rows x 32 cols as 128 lines x 128B; line=row>>1,
  // slot=(2*lk+(row&1))^((row>>1)&7) (R4/R10-proven). Read offset per lane:
  const int slot = ((2 * lk + (fr & 1)) ^ ((fr >> 1) & 7)) << 4;
  const int aoff = whm * 8192 + (fr >> 1) * 128 + slot;

  // A staging (inverse swizzle on global source, linear DMA dest):
  const int line = tid >> 3;
  const int v = (tid & 7) ^ (line & 7);
  const int srow0 = 2 * line + (v & 1);
  const int srow1 = srow0 + 128;
  const int scol = (v >> 1) * 8;
  const int ldd0 = tid * 16;
  const int ldd1 = ldd0 + 8192;
  const __hip_bfloat16* const Ag = A + m0 * D;

  auto stgA = [&](int s) {   // 2 x global_load_lds(16B)
    const __hip_bfloat16* s0 = Ag + (size_t)srow0 * D + s * 32 + scol;
    const __hip_bfloat16* s1 = Ag + (size_t)srow1 * D + s * 32 + scol;
    char* q = (char*)sA + ((s & 3) << 14);
    __builtin_amdgcn_global_load_lds(GLP(s0), LDSP(q + ldd0), 16, 0, 0);
    __builtin_amdgcn_global_load_lds(GLP(s1), LDSP(q + ldd1), 16, 0, 0);
  };

  // B-direct: wave (wid&3) owns frags nfb..nfb+3; lane-contiguous 1KB per frag.
  const __hip_bfloat16* const WFb = WF + (size_t)blockIdx.y * (64 * 16 * 64 * 8)
                                       + ((wid & 3) * 4) * 512 + l * 8;
  bf16x8 a[8], bE[4], bO[4];
  f32x4 acc[8][4] = {};

  auto ldB = [&](int s, bf16x8* dst) {   // 4 x global_load_dwordx4
    const __hip_bfloat16* p = WFb + (size_t)s * 8192;
#pragma unroll
    for (int ni = 0; ni < 4; ++ni) dst[ni] = *(const bf16x8*)(p + ni * 512);
  };
  auto rdA = [&](int s) {                // 8 linear-ish ds_read_b128
    const char* pa = (const char*)sA + ((s & 3) << 14) + aoff;
#pragma unroll
    for (int mi = 0; mi < 8; ++mi) a[mi] = *(const bf16x8*)(pa + mi * 1024);
  };
  auto mma = [&](const bf16x8* br) {
    __builtin_amdgcn_s_setprio(1);
#pragma unroll
    for (int mi = 0; mi < 8; ++mi)
#pragma unroll
      for (int ni = 0; ni < 4; ++ni)
        acc[mi][ni] = __builtin_amdgcn_mfma_f32_16x16x32_bf16(a[mi], br[ni], acc[mi][ni], 0, 0, 0);
    __builtin_amdgcn_s_setprio(0);
  };

  // prologue: [stgA0(2), ldB0(4), stgA1(2), ldB1(4)] = 12 outstanding
  stgA(0); ldB(0, bE); stgA(1); ldB(1, bO);

  // body(s): vmcnt(6) retires exactly {stgA(s), ldB(s)} (oldest 6), keeps s+1's 6 in
  // flight. BAR makes A-LDS visible to all waves. ldB(s+2) AFTER mma(s): no WAR, and
  // its latency is covered by body(s+1). Ring-4: stgA(s+2) never targets a buffer
  // read this body or next; prior reads of that buffer retired 2 barriers ago.
  for (int sp = 0; sp < 31; ++sp) {
    const int s0 = 2 * sp;
    S_VMCNT(6);
    BAR(); MEMFENCE(); SCHED_FENCE();
    rdA(s0);
    stgA(s0 + 2);
    mma(bE);
    ldB(s0 + 2, bE);
    S_VMCNT(6);
    BAR(); MEMFENCE(); SCHED_FENCE();
    rdA(s0 + 1);
    stgA(s0 + 3);
    mma(bO);
    ldB(s0 + 3, bO);
  }
  // s=62: top outstanding = [62's(6), 63's(6)]
  S_VMCNT(6);
  BAR(); MEMFENCE(); SCHED_FENCE();
  rdA(62);
  mma(bE);
  // s=63: top outstanding = [stgA63(2), ldB63(4)]
  S_VMCNT(0);
  BAR(); MEMFENCE(); SCHED_FENCE();
  rdA(63);
  mma(bO);

  // epilogue: bias + gelu (C/D: col=lane&15, row=(lane>>4)*4+reg)
  float bv[4];
#pragma unroll
  for (int ni = 0; ni < 4; ++ni) bv[ni] = bias[n0 + wn + ni * 16 + fr];
#pragma unroll
  for (int mi = 0; mi < 8; ++mi) {
    const size_t rbase = m0 + whm * 128 + mi * 16 + lk * 4;
#pragma unroll
    for (int rr = 0; rr < 4; ++rr) {
      const size_t ro = (rbase + rr) * D + n0 + wn + fr;
#pragma unroll
      for (int ni = 0; ni < 4; ++ni) {
        const float val = gelu_f(acc[mi][ni][rr] + bv[ni]);
        if constexpr (BFO)
          ((__hip_bfloat16*)Cout)[ro + ni * 16] = __float2bfloat16(val);
        else
          ((float*)Cout)[ro + ni * 16] = val;
      }
    }
  }
}

// ---------------- LN2 (f32 in-place fallback) ----------------
__global__ __launch_bounds__(256) void ln2_kernel(
    float* __restrict__ C, const float* __restrict__ g, const float* __restrict__ b) {
  const int tid = threadIdx.x;
  const size_t row = blockIdx.x;
  float4* cr = (float4*)(C + row * D);
  float4 v0 = cr[2 * tid], v1 = cr[2 * tid + 1];
  float s  = v0.x + v0.y + v0.z + v0.w + v1.x + v1.y + v1.z + v1.w;
  float ss = v0.x*v0.x + v0.y*v0.y + v0.z*v0.z + v0.w*v0.w
           + v1.x*v1.x + v1.y*v1.y + v1.z*v1.z + v1.w*v1.w;
#pragma unroll
  for (int off = 32; off > 0; off >>= 1) {
    s  += __shfl_down(s, off, 64);
    ss += __shfl_down(ss, off, 64);
  }
  __shared__ float red[8];
  const int w = tid >> 6;
  if ((tid & 63) == 0) { red[w] = s; red[w + 4] = ss; }
  __syncthreads();
  s  = red[0] + red[1] + red[2] + red[3];
  ss = red[4] + red[5] + red[6] + red[7];
  const float mu  = s * (1.0f / D);
  const float var = ss * (1.0f / D) - mu * mu;
  const float inv = rsqrtf(var + 1e-5f);
  const float4* gv = (const float4*)g;
  const float4* bv = (const float4*)b;
  float4 g0 = gv[2 * tid], g1 = gv[2 * tid + 1];
  float4 b0 = bv[2 * tid], b1 = bv[2 * tid + 1];
  float4 o0, o1;
  o0.x = (v0.x - mu) * inv * g0.x + b0.x;
  o0.y = (v0.y - mu) * inv * g0.y + b0.y;
  o0.z = (v0.z - mu) * inv * g0.z + b0.z;
  o0.w = (v0.w - mu) * inv * g0.w + b0.w;
  o1.x = (v1.x - mu) * inv * g1.x + b1.x;
  o1.y = (v1.y - mu) * inv * g1.y + b1.y;
  o1.z = (v1.z - mu) * inv * g1.z + b1.z;
  o1.w = (v1.w - mu) * inv * g1.w + b1.w;
  cr[2 * tid] = o0;
  cr[2 * tid + 1] = o1;
}

// ---------------- LN2 from bf16 h2 -> f32 out ----------------
__global__ __launch_bounds__(256) void ln2b_kernel(
    const __hip_bfloat16* __restrict__ H, const float* __restrict__ g,
    const float* __restrict__ b, float* __restrict__ out) {
  const int tid = threadIdx.x;
  const size_t row = blockIdx.x;
  const uint4 hv = ((const uint4*)(H + row * D))[tid];   // 8 bf16
  float v[8];
  const unsigned wds[4] = {hv.x, hv.y, hv.z, hv.w};
#pragma unroll
  for (int i = 0; i < 4; ++i) {
    unsigned lo = (wds[i] & 0xffffu) << 16;
    unsigned hi = wds[i] & 0xffff0000u;
    v[2 * i]     = __builtin_bit_cast(float, lo);
    v[2 * i + 1] = __builtin_bit_cast(float, hi);
  }
  float s = 0.f, ss = 0.f;
#pragma unroll
  for (int i = 0; i < 8; ++i) { s += v[i]; ss += v[i] * v[i]; }
#pragma unroll
  for (int off = 32; off > 0; off >>= 1) {
    s  += __shfl_down(s, off, 64);
    ss += __shfl_down(ss, off, 64);
  }
  __shared__ float red[8];
  const int w = tid >> 6;
  if ((tid & 63) == 0) { red[w] = s; red[w + 4] = ss; }
  __syncthreads();
  s  = red[0] + red[1] + red[2] + red[3];
  ss = red[4] + red[5] + red[6] + red[7];
  const float mu  = s * (1.0f / D);
  const float var = ss * (1.0f / D) - mu * mu;
  const float inv = rsqrtf(var + 1e-5f);
  const float4* gv = (const float4*)g;
  const float4* bv = (const float4*)b;
  float4 g0 = gv[2 * tid], g1 = gv[2 * tid + 1];
  float4 b0 = bv[2 * tid], b1 = bv[2 * tid + 1];
  float4 o0, o1;
  o0.x = (v[0] - mu) * inv * g0.x + b0.x;
  o0.y = (v[1] - mu) * inv * g0.y + b0.y;
  o0.z = (v[2] - mu) * inv * g0.z + b0.z;
  o0.w = (v[3] - mu) * inv * g0.w + b0.w;
  o1.x = (v[4] - mu) * inv * g1.x + b1.x;
  o1.y = (v[5] - mu) * inv * g1.y + b1.y;
  o1.z = (v[6] - mu) * inv * g1.z + b1.z;
  o1.w = (v[7] - mu) * inv * g1.w + b1.w;
  float4* orow = (float4*)(out + row * D);
  orow[2 * tid] = o0;
  orow[2 * tid + 1] = o1;
}

extern "C" void kernel_launch(void* const* d_in, const int* in_sizes, int n_in,
                              void* d_out, int out_size, void* d_ws, size_t ws_size,
                              hipStream_t stream) {
  const float* x  = (const float*)d_in[0];
  const float* W  = (const float*)d_in[1];
  const float* bW = (const float*)d_in[2];
  const float* g1 = (const float*)d_in[3];
  const float* b1 = (const float*)d_in[4];
  const float* g2 = (const float*)d_in[5];
  const float* b2 = (const float*)d_in[6];
  float* out = (float*)d_out;

  __hip_bfloat16* Abf = (__hip_bfloat16*)d_ws;                    // 67MB
  __hip_bfloat16* WFb = Abf + (size_t)MROWS * D;                  // +8.4MB (pre-fragmented)
  __hip_bfloat16* H2  = WFb + (size_t)D * D;                      // +67MB (optional)
  const size_t need = ((size_t)MROWS * D * 2 + (size_t)D * D) * sizeof(__hip_bfloat16);

  ln1_kernel<<<MROWS, 256, 0, stream>>>(x, g1, b1, Abf);
  cvtf_kernel<<<(D * D / 8) / 256, 256, 0, stream>>>(W, WFb);
  dim3 grid(MROWS / BMT, D / BNT);
  if (ws_size >= need) {
    gemm_kernel<true><<<grid, 512, 0, stream>>>(Abf, WFb, bW, (void*)H2);
    ln2b_kernel<<<MROWS, 256, 0, stream>>>(H2, g2, b2, out);
  } else {
    gemm_kernel<false><<<grid, 512, 0, stream>>>(Abf, WFb, bW, (void*)out);
    ln2_kernel<<<MROWS, 256, 0, stream>>>(out, g2, b2);
  }
}